// Round 1
// baseline (23838.417 us; speedup 1.0000x reference)
//
#include <hip/hip_runtime.h>

// Problem constants (H=512, A=16, L=3, B=256, T=512)
#define HD 512
#define AD 16
#define BD 256
#define TD 512

using short8  = __attribute__((ext_vector_type(8))) short;
using float4v = __attribute__((ext_vector_type(4))) float;
using ushort4v = __attribute__((ext_vector_type(4))) unsigned short;
typedef unsigned short u16;

__device__ __forceinline__ u16 f2bf(float f) {
  union { float f; unsigned u; } v; v.f = f;
  unsigned r = v.u + 0x7fffu + ((v.u >> 16) & 1u);
  return (u16)(r >> 16);
}
__device__ __forceinline__ float bf2f(u16 u) {
  union { unsigned u; float f; } c; c.u = ((unsigned)u) << 16; return c.f;
}

// ---------------- fp32 -> bf16 convert ----------------
__global__ __launch_bounds__(256) void cvt_bf16(const float* __restrict__ in,
                                                u16* __restrict__ out, int n) {
  int i = blockIdx.x * 256 + threadIdx.x;
  int stride = gridDim.x * 256;
  for (; i < n; i += stride) out[i] = f2bf(in[i]);
}

// ---------------- GEMM (M x 512) @ (512 x 512)^T + bias -> LayerNorm -> ReLU -> bf16 ----------------
// Block: 256 threads, tile M=64, N=512 (full row for LN). K=512 in 16 chunks of 32.
template <bool AF32>
__global__ __launch_bounds__(256) void gemm_ln_relu(
    const void* __restrict__ Ap, const u16* __restrict__ W,
    const float* __restrict__ bias, const float* __restrict__ gam,
    const float* __restrict__ bet, u16* __restrict__ Y) {
  const int r0 = blockIdx.x * 64;
  const int tid = threadIdx.x;
  const int wave = tid >> 6, lane = tid & 63;
  const int lq = lane >> 4, ln16 = lane & 15;

  __shared__ u16 As[64 * 40];     // pad to 40 bf16/row: 16B-aligned rows, 2-way-max bank alias
  __shared__ u16 Bs[512 * 40];
  __shared__ float partial[64][4][2];
  __shared__ float murs[64][2];

  float4v acc[4][8];
#pragma unroll
  for (int i = 0; i < 4; ++i)
#pragma unroll
    for (int j = 0; j < 8; ++j) acc[i][j] = (float4v){0.f, 0.f, 0.f, 0.f};

  for (int kk = 0; kk < 16; ++kk) {
    __syncthreads();
    if (AF32) {
      const float* Af = (const float*)Ap;
#pragma unroll
      for (int it = 0; it < 2; ++it) {
        int q = tid + it * 256;           // 512 chunks of 4 floats
        int row = q >> 3, ko = (q & 7) * 4;
        float4v v = *(const float4v*)(Af + (r0 + row) * 512 + kk * 32 + ko);
        ushort4v o;
        o[0] = f2bf(v[0]); o[1] = f2bf(v[1]); o[2] = f2bf(v[2]); o[3] = f2bf(v[3]);
        *(ushort4v*)(&As[row * 40 + ko]) = o;
      }
    } else {
      const u16* Ab = (const u16*)Ap;
      int row = tid >> 2, ko = (tid & 3) * 8;
      *(short8*)(&As[row * 40 + ko]) =
          *(const short8*)(Ab + (r0 + row) * 512 + kk * 32 + ko);
    }
#pragma unroll
    for (int it = 0; it < 8; ++it) {
      int q = tid + it * 256;             // 2048 chunks of 8 bf16
      int row = q >> 2, ko = (q & 3) * 8;
      *(short8*)(&Bs[row * 40 + ko]) =
          *(const short8*)(W + row * 512 + kk * 32 + ko);
    }
    __syncthreads();
    short8 afr[4];
#pragma unroll
    for (int mt = 0; mt < 4; ++mt)
      afr[mt] = *(const short8*)(&As[(mt * 16 + ln16) * 40 + lq * 8]);
#pragma unroll
    for (int nt = 0; nt < 8; ++nt) {
      short8 bfr = *(const short8*)(&Bs[(wave * 128 + nt * 16 + ln16) * 40 + lq * 8]);
#pragma unroll
      for (int mt = 0; mt < 4; ++mt)
        acc[mt][nt] = __builtin_amdgcn_mfma_f32_16x16x32_bf16(afr[mt], bfr, acc[mt][nt], 0, 0, 0);
    }
  }

  // epilogue: +bias, LayerNorm over N=512, *g+b, ReLU, bf16 store
  float gv[8], bv[8], av[8];
#pragma unroll
  for (int nt = 0; nt < 8; ++nt) {
    int c = wave * 128 + nt * 16 + ln16;
    gv[nt] = gam[c]; bv[nt] = bet[c]; av[nt] = bias[c];
  }
#pragma unroll
  for (int mt = 0; mt < 4; ++mt)
#pragma unroll
    for (int nt = 0; nt < 8; ++nt)
#pragma unroll
      for (int r = 0; r < 4; ++r) acc[mt][nt][r] += av[nt];

#pragma unroll
  for (int mt = 0; mt < 4; ++mt) {
#pragma unroll
    for (int r = 0; r < 4; ++r) {
      float s = 0.f, ss = 0.f;
#pragma unroll
      for (int nt = 0; nt < 8; ++nt) { float v = acc[mt][nt][r]; s += v; ss += v * v; }
#pragma unroll
      for (int off = 1; off < 16; off <<= 1) { s += __shfl_xor(s, off); ss += __shfl_xor(ss, off); }
      if (ln16 == 0) {
        int m = mt * 16 + lq * 4 + r;
        partial[m][wave][0] = s; partial[m][wave][1] = ss;
      }
    }
  }
  __syncthreads();
  if (tid < 64) {
    float s = partial[tid][0][0] + partial[tid][1][0] + partial[tid][2][0] + partial[tid][3][0];
    float ss = partial[tid][0][1] + partial[tid][1][1] + partial[tid][2][1] + partial[tid][3][1];
    float mu = s * (1.f / 512.f);
    float var = ss * (1.f / 512.f) - mu * mu;
    murs[tid][0] = mu;
    murs[tid][1] = rsqrtf(var + 1e-5f);
  }
  __syncthreads();
#pragma unroll
  for (int mt = 0; mt < 4; ++mt) {
#pragma unroll
    for (int r = 0; r < 4; ++r) {
      int m = mt * 16 + lq * 4 + r;
      float mu = murs[m][0], rs = murs[m][1];
#pragma unroll
      for (int nt = 0; nt < 8; ++nt) {
        int c = wave * 128 + nt * 16 + ln16;
        float v = (acc[mt][nt][r] - mu) * rs * gv[nt] + bv[nt];
        Y[(r0 + m) * 512 + c] = f2bf(fmaxf(v, 0.f));
      }
    }
  }
}

// ---------------- persistent GRU scan ----------------
// grid = 256 blocks: bg = blockIdx>>5 (8 batch groups x 32 rows), cg = blockIdx&31 (32 channel
// groups x 16 ch). Wih/Whh slices (48 gate-rows x 512, bf16) resident in LDS. gi computed in-step.
// Sync: per-batch-group 32 flags; release store after step, relaxed poll + fence before reading h.
__global__ __launch_bounds__(256) void gru_scan(
    const u16* __restrict__ emb, const u16* __restrict__ wih,
    const u16* __restrict__ whh, const float* __restrict__ bih,
    const float* __restrict__ bhh, const float* __restrict__ hidden,
    const int* __restrict__ dones, float* __restrict__ outs,
    float* __restrict__ hfin, u16* __restrict__ hbf, int* __restrict__ flags) {
  const int bg = blockIdx.x >> 5;
  const int cg = blockIdx.x & 31;
  const int c0 = cg * 16;
  const int b0 = bg * 32;
  const int tid = threadIdx.x;
  const int wave = tid >> 6, lane = tid & 63;
  const int lq = lane >> 4, ln16 = lane & 15;

  __shared__ u16 Wi[48 * 520];   // pad 520: 16B-aligned rows, 2-way-max alias
  __shared__ u16 Wh[48 * 520];
  __shared__ u16 Hs[32 * 520];   // staged masked h_{t-1} (bf16)
  __shared__ float scr[2][32][52];
  __shared__ float biasl[2][48];

  for (int q = tid; q < 48 * 64; q += 256) {
    int row = q >> 6;
    int ch = (q & 63) * 8;
    int gr = (row >> 4) * 512 + c0 + (row & 15);   // gate-major weight row
    *(short8*)(&Wi[row * 520 + ch]) = *(const short8*)(wih + gr * 512 + ch);
    *(short8*)(&Wh[row * 520 + ch]) = *(const short8*)(whh + gr * 512 + ch);
  }
  if (tid < 96) {
    int g = (tid >= 48) ? 1 : 0;
    int i = tid - g * 48;
    const float* src = g ? bhh : bih;
    biasl[g][i] = src[(i >> 4) * 512 + c0 + (i & 15)];
  }
  __syncthreads();

  // unit descriptors: u = wave + ui*4 over 12 units (2 gemms x 2 m-tiles x 3 n-tiles)
  int ug[3], umt[3], unt[3];
#pragma unroll
  for (int ui = 0; ui < 3; ++ui) {
    int u = wave + ui * 4;
    ug[ui] = u / 6;
    int rem = u % 6;
    umt[ui] = rem / 3;
    unt[ui] = rem % 3;
  }

  for (int t = 0; t < TD; ++t) {
    // --- gi units (independent of h; run before sync to hide latency) ---
#pragma unroll
    for (int ui = 0; ui < 3; ++ui) {
      if (ug[ui] != 0) continue;
      float4v acc = {0.f, 0.f, 0.f, 0.f};
      const int b = b0 + umt[ui] * 16 + ln16;
      const u16* arp = emb + (b * 512 + t) * 512 + lq * 8;
      const u16* brp = &Wi[(unt[ui] * 16 + ln16) * 520 + lq * 8];
#pragma unroll
      for (int kk = 0; kk < 16; ++kk) {
        short8 af = *(const short8*)(arp + kk * 32);
        short8 bf = *(const short8*)(brp + kk * 32);
        acc = __builtin_amdgcn_mfma_f32_16x16x32_bf16(af, bf, acc, 0, 0, 0);
      }
#pragma unroll
      for (int r = 0; r < 4; ++r)
        scr[0][umt[ui] * 16 + lq * 4 + r][unt[ui] * 16 + ln16] = acc[r];
    }

    // --- wait for all 32 channel blocks of this batch group to finish step t-1 ---
    if (t > 0) {
      int* fl = flags + bg * 32;
      int guard = 0;
      for (;;) {
        int f = __hip_atomic_load(fl + (lane & 31), __ATOMIC_RELAXED, __HIP_MEMORY_SCOPE_AGENT);
        if (__ballot(f >= t) == ~0ull) break;
        if (++guard > (1 << 25)) break;   // fail-safe: never hang the bench
      }
      __threadfence();  // acquire: make other blocks' h/hbf writes visible
    }

    // --- stage masked h_{t-1} (bf16) into LDS ---
#pragma unroll
    for (int i = 0; i < 8; ++i) {
      int q = tid + i * 256;           // 2048 chunks of 8
      int row = q >> 6;                // 0..31
      int ch = (q & 63) * 8;
      int b = b0 + row;
      bool dn = dones[b * 512 + t] != 0;
      short8 v;
      if (t == 0) {
        const float* hp = hidden + b * 512 + ch;
        float4v h0 = *(const float4v*)(hp);
        float4v h1 = *(const float4v*)(hp + 4);
        v[0] = (short)f2bf(h0[0]); v[1] = (short)f2bf(h0[1]);
        v[2] = (short)f2bf(h0[2]); v[3] = (short)f2bf(h0[3]);
        v[4] = (short)f2bf(h1[0]); v[5] = (short)f2bf(h1[1]);
        v[6] = (short)f2bf(h1[2]); v[7] = (short)f2bf(h1[3]);
      } else {
        v = *(const short8*)(hbf + ((t - 1) & 1) * 131072 + b * 512 + ch);
      }
      if (dn) { short8 zz = {0, 0, 0, 0, 0, 0, 0, 0}; v = zz; }
      *(short8*)(&Hs[row * 520 + ch]) = v;
    }
    __syncthreads();

    // --- gh units ---
#pragma unroll
    for (int ui = 0; ui < 3; ++ui) {
      if (ug[ui] != 1) continue;
      float4v acc = {0.f, 0.f, 0.f, 0.f};
      const u16* arp = &Hs[(umt[ui] * 16 + ln16) * 520 + lq * 8];
      const u16* brp = &Wh[(unt[ui] * 16 + ln16) * 520 + lq * 8];
#pragma unroll
      for (int kk = 0; kk < 16; ++kk) {
        short8 af = *(const short8*)(arp + kk * 32);
        short8 bf = *(const short8*)(brp + kk * 32);
        acc = __builtin_amdgcn_mfma_f32_16x16x32_bf16(af, bf, acc, 0, 0, 0);
      }
#pragma unroll
      for (int r = 0; r < 4; ++r)
        scr[1][umt[ui] * 16 + lq * 4 + r][unt[ui] * 16 + ln16] = acc[r];
    }
    __syncthreads();

    // --- elementwise GRU cell (fp32 state path) ---
    for (int e = tid; e < 512; e += 256) {
      int m = e >> 4, c = e & 15;
      int b = b0 + m;
      bool dn = dones[b * 512 + t] != 0;
      float h = 0.f;
      if (!dn)
        h = (t == 0) ? hidden[b * 512 + c0 + c]
                     : outs[((t - 1) * 256 + b) * 512 + c0 + c];
      float ir  = scr[0][m][c]      + biasl[0][c];
      float iz  = scr[0][m][c + 16] + biasl[0][c + 16];
      float inn = scr[0][m][c + 32] + biasl[0][c + 32];
      float hr  = scr[1][m][c]      + biasl[1][c];
      float hz  = scr[1][m][c + 16] + biasl[1][c + 16];
      float hn  = scr[1][m][c + 32] + biasl[1][c + 32];
      float rg = 1.f / (1.f + expf(-(ir + hr)));
      float z  = 1.f / (1.f + expf(-(iz + hz)));
      float nn = tanhf(inn + rg * hn);
      float hv = (1.f - z) * nn + z * h;
      outs[(t * 256 + b) * 512 + c0 + c] = hv;
      hbf[(t & 1) * 131072 + b * 512 + c0 + c] = f2bf(hv);
      if (t == TD - 1) hfin[b * 512 + c0 + c] = hv;
    }
    __syncthreads();   // drains vmcnt before the release

    if (tid == 0 && t < TD - 1) {
      __threadfence();  // release: flush this XCD's dirty lines device-wide
      __hip_atomic_store(flags + bg * 32 + cg, t + 1, __ATOMIC_RELEASE, __HIP_MEMORY_SCOPE_AGENT);
    }
  }
}

// ---------------- final A=16 projection + avail mask ----------------
__global__ __launch_bounds__(256) void head_logits(
    const u16* __restrict__ am, const float* __restrict__ w2,
    const float* __restrict__ b2, const float* __restrict__ avail,
    float* __restrict__ out) {
  int r = blockIdx.x * 16 + (threadIdx.x >> 4);   // row in (t,b) order
  int a = threadIdx.x & 15;
  int t = r >> 8, b = r & 255;
  const u16* ar = am + r * 512;
  const float* wr = w2 + a * 512;
  float acc = 0.f;
  for (int k = 0; k < 512; k += 8) {
    short8 v = *(const short8*)(ar + k);
    float4v w0 = *(const float4v*)(wr + k);
    float4v w1 = *(const float4v*)(wr + k + 4);
    acc += bf2f((u16)v[0]) * w0[0] + bf2f((u16)v[1]) * w0[1] +
           bf2f((u16)v[2]) * w0[2] + bf2f((u16)v[3]) * w0[3] +
           bf2f((u16)v[4]) * w1[0] + bf2f((u16)v[5]) * w1[1] +
           bf2f((u16)v[6]) * w1[2] + bf2f((u16)v[7]) * w1[3];
  }
  int oi = (b * 512 + t) * 16 + a;   // [B,T,A] flat
  float avv = avail[oi];
  out[oi] = acc + b2[a] - (1.f - avv) * 1e10f;
}

extern "C" void kernel_launch(void* const* d_in, const int* in_sizes, int n_in,
                              void* d_out, int out_size, void* d_ws, size_t ws_size,
                              hipStream_t stream) {
  (void)in_sizes; (void)n_in; (void)out_size; (void)ws_size;
  const float* hidden = (const float*)d_in[0];
  const float* obs    = (const float*)d_in[1];
  const int*   dones  = (const int*)d_in[2];
  const float* avail  = (const float*)d_in[3];
  const float* in_w   = (const float*)d_in[4];
  const float* in_b   = (const float*)d_in[5];
  const float* ln_g   = (const float*)d_in[6];
  const float* ln_b   = (const float*)d_in[7];
  const float* gwih   = (const float*)d_in[8];
  const float* gwhh   = (const float*)d_in[9];
  const float* gbih   = (const float*)d_in[10];
  const float* gbhh   = (const float*)d_in[11];
  const float* am1w   = (const float*)d_in[12];
  const float* am1b   = (const float*)d_in[13];
  const float* amg    = (const float*)d_in[14];
  const float* amb    = (const float*)d_in[15];
  const float* am2w   = (const float*)d_in[16];
  const float* am2b   = (const float*)d_in[17];

  char* ws = (char*)d_ws;
  u16*   embA  = (u16*)(ws);                       // 128 MiB [B*T,512] bf16
  u16*   embB  = (u16*)(ws + 134217728);           // 128 MiB
  float* outs  = (float*)(ws + 268435456);         // 256 MiB [T,B,512] f32
  u16*   w_in  = (u16*)(ws + 536870912);           // bf16 weights
  u16*   w_ih  = w_in + 786432;
  u16*   w_hh  = w_ih + 786432;
  u16*   w_a1  = w_hh + 786432;
  int*   flags = (int*)(ws + 536870912 + 5242880); // 1 KiB
  u16*   hbf   = (u16*)(ws + 536870912 + 5242880 + 1024); // 512 KiB h ping-pong bf16

  hipMemsetAsync(flags, 0, 1024, stream);
  cvt_bf16<<<1024, 256, 0, stream>>>(in_w, w_in, 786432);
  cvt_bf16<<<1024, 256, 0, stream>>>(gwih, w_ih, 786432);
  cvt_bf16<<<1024, 256, 0, stream>>>(gwhh, w_hh, 786432);
  cvt_bf16<<<512, 256, 0, stream>>>(am1w, w_a1, 262144);

  // MLP: Linear -> LN -> ReLU x3  (rows in (b,t) order, same as obs)
  gemm_ln_relu<true ><<<2048, 256, 0, stream>>>(obs,  w_in,          in_b,        ln_g,        ln_b,        embA);
  gemm_ln_relu<false><<<2048, 256, 0, stream>>>(embA, w_in + 262144, in_b + 512,  ln_g + 512,  ln_b + 512,  embB);
  gemm_ln_relu<false><<<2048, 256, 0, stream>>>(embB, w_in + 524288, in_b + 1024, ln_g + 1024, ln_b + 1024, embA);

  // GRU scan (persistent, 256 blocks, group-local flag sync)
  gru_scan<<<256, 256, 0, stream>>>(embA, w_ih, w_hh, gbih, gbhh, hidden, dones,
                                    outs, (float*)d_out, hbf, flags);

  // actor head: Linear -> LN -> ReLU (rows in (t,b) order), then A=16 projection + mask
  gemm_ln_relu<true ><<<2048, 256, 0, stream>>>(outs, w_a1, am1b, amg, amb, embB);
  head_logits<<<8192, 256, 0, stream>>>(embB, am2w, am2b, avail, (float*)d_out + 131072);
}

// Round 2
// 7584.760 us; speedup vs baseline: 3.1429x; 3.1429x over previous
//
#include <hip/hip_runtime.h>

// Problem constants (H=512, A=16, L=3, B=256, T=512)
#define HD 512
#define AD 16
#define BD 256
#define TD 512

using short8  = __attribute__((ext_vector_type(8))) short;
using float4v = __attribute__((ext_vector_type(4))) float;
using ushort4v = __attribute__((ext_vector_type(4))) unsigned short;
typedef unsigned short u16;
typedef unsigned long long u64;

__device__ __forceinline__ u16 f2bf(float f) {
  union { float f; unsigned u; } v; v.f = f;
  unsigned r = v.u + 0x7fffu + ((v.u >> 16) & 1u);
  return (u16)(r >> 16);
}
__device__ __forceinline__ float bf2f(u16 u) {
  union { unsigned u; float f; } c; c.u = ((unsigned)u) << 16; return c.f;
}

// ---------------- fp32 -> bf16 convert ----------------
__global__ __launch_bounds__(256) void cvt_bf16(const float* __restrict__ in,
                                                u16* __restrict__ out, int n) {
  int i = blockIdx.x * 256 + threadIdx.x;
  int stride = gridDim.x * 256;
  for (; i < n; i += stride) out[i] = f2bf(in[i]);
}

// ---------------- GEMM (M x 512) @ (512 x 512)^T + bias -> LayerNorm -> ReLU -> bf16 ----------------
// Block: 256 threads, tile M=64, N=512 (full row for LN). K=512 in 16 chunks of 32.
template <bool AF32>
__global__ __launch_bounds__(256) void gemm_ln_relu(
    const void* __restrict__ Ap, const u16* __restrict__ W,
    const float* __restrict__ bias, const float* __restrict__ gam,
    const float* __restrict__ bet, u16* __restrict__ Y) {
  const int r0 = blockIdx.x * 64;
  const int tid = threadIdx.x;
  const int wave = tid >> 6, lane = tid & 63;
  const int lq = lane >> 4, ln16 = lane & 15;

  __shared__ u16 As[64 * 40];     // pad to 40 bf16/row: 16B-aligned rows, 2-way-max bank alias
  __shared__ u16 Bs[512 * 40];
  __shared__ float partial[64][4][2];
  __shared__ float murs[64][2];

  float4v acc[4][8];
#pragma unroll
  for (int i = 0; i < 4; ++i)
#pragma unroll
    for (int j = 0; j < 8; ++j) acc[i][j] = (float4v){0.f, 0.f, 0.f, 0.f};

  for (int kk = 0; kk < 16; ++kk) {
    __syncthreads();
    if (AF32) {
      const float* Af = (const float*)Ap;
#pragma unroll
      for (int it = 0; it < 2; ++it) {
        int q = tid + it * 256;           // 512 chunks of 4 floats
        int row = q >> 3, ko = (q & 7) * 4;
        float4v v = *(const float4v*)(Af + (r0 + row) * 512 + kk * 32 + ko);
        ushort4v o;
        o[0] = f2bf(v[0]); o[1] = f2bf(v[1]); o[2] = f2bf(v[2]); o[3] = f2bf(v[3]);
        *(ushort4v*)(&As[row * 40 + ko]) = o;
      }
    } else {
      const u16* Ab = (const u16*)Ap;
      int row = tid >> 2, ko = (tid & 3) * 8;
      *(short8*)(&As[row * 40 + ko]) =
          *(const short8*)(Ab + (r0 + row) * 512 + kk * 32 + ko);
    }
#pragma unroll
    for (int it = 0; it < 8; ++it) {
      int q = tid + it * 256;             // 2048 chunks of 8 bf16
      int row = q >> 2, ko = (q & 3) * 8;
      *(short8*)(&Bs[row * 40 + ko]) =
          *(const short8*)(W + row * 512 + kk * 32 + ko);
    }
    __syncthreads();
    short8 afr[4];
#pragma unroll
    for (int mt = 0; mt < 4; ++mt)
      afr[mt] = *(const short8*)(&As[(mt * 16 + ln16) * 40 + lq * 8]);
#pragma unroll
    for (int nt = 0; nt < 8; ++nt) {
      short8 bfr = *(const short8*)(&Bs[(wave * 128 + nt * 16 + ln16) * 40 + lq * 8]);
#pragma unroll
      for (int mt = 0; mt < 4; ++mt)
        acc[mt][nt] = __builtin_amdgcn_mfma_f32_16x16x32_bf16(afr[mt], bfr, acc[mt][nt], 0, 0, 0);
    }
  }

  // epilogue: +bias, LayerNorm over N=512, *g+b, ReLU, bf16 store
  float gv[8], bv[8], av[8];
#pragma unroll
  for (int nt = 0; nt < 8; ++nt) {
    int c = wave * 128 + nt * 16 + ln16;
    gv[nt] = gam[c]; bv[nt] = bet[c]; av[nt] = bias[c];
  }
#pragma unroll
  for (int mt = 0; mt < 4; ++mt)
#pragma unroll
    for (int nt = 0; nt < 8; ++nt)
#pragma unroll
      for (int r = 0; r < 4; ++r) acc[mt][nt][r] += av[nt];

#pragma unroll
  for (int mt = 0; mt < 4; ++mt) {
#pragma unroll
    for (int r = 0; r < 4; ++r) {
      float s = 0.f, ss = 0.f;
#pragma unroll
      for (int nt = 0; nt < 8; ++nt) { float v = acc[mt][nt][r]; s += v; ss += v * v; }
#pragma unroll
      for (int off = 1; off < 16; off <<= 1) { s += __shfl_xor(s, off); ss += __shfl_xor(ss, off); }
      if (ln16 == 0) {
        int m = mt * 16 + lq * 4 + r;
        partial[m][wave][0] = s; partial[m][wave][1] = ss;
      }
    }
  }
  __syncthreads();
  if (tid < 64) {
    float s = partial[tid][0][0] + partial[tid][1][0] + partial[tid][2][0] + partial[tid][3][0];
    float ss = partial[tid][0][1] + partial[tid][1][1] + partial[tid][2][1] + partial[tid][3][1];
    float mu = s * (1.f / 512.f);
    float var = ss * (1.f / 512.f) - mu * mu;
    murs[tid][0] = mu;
    murs[tid][1] = rsqrtf(var + 1e-5f);
  }
  __syncthreads();
#pragma unroll
  for (int mt = 0; mt < 4; ++mt) {
#pragma unroll
    for (int r = 0; r < 4; ++r) {
      int m = mt * 16 + lq * 4 + r;
      float mu = murs[m][0], rs = murs[m][1];
#pragma unroll
      for (int nt = 0; nt < 8; ++nt) {
        int c = wave * 128 + nt * 16 + ln16;
        float v = (acc[mt][nt][r] - mu) * rs * gv[nt] + bv[nt];
        Y[(r0 + m) * 512 + c] = f2bf(fmaxf(v, 0.f));
      }
    }
  }
}

// ---------------- persistent GRU scan ----------------
// grid = 256 blocks: bg = blockIdx>>5 (8 batch groups x 32 rows), cg = blockIdx&31 (32 channel
// groups x 16 ch). Wih/Whh slices resident in LDS. gi computed in-step (pre-sync prefetch).
// Sync: fence-FREE. Cross-block h goes through relaxed agent-scope atomics (sc1, coherent at
// IF$; bypasses stale per-XCD L2). Release = s_waitcnt(0) + barrier + relaxed atomicAdd on a
// per-(bg,t) counter; acquire = poll that one word. No buffer_wbl2 / buffer_inv ever -> L2
// stays warm for emb/dones across all 512 steps.
__global__ __launch_bounds__(256) void gru_scan(
    const u16* __restrict__ emb, const u16* __restrict__ wih,
    const u16* __restrict__ whh, const float* __restrict__ bih,
    const float* __restrict__ bhh, const float* __restrict__ hidden,
    const int* __restrict__ dones, float* __restrict__ outs,
    float* __restrict__ hfin, u64* __restrict__ hpk, int* __restrict__ cnt) {
  const int bg = blockIdx.x >> 5;
  const int cg = blockIdx.x & 31;
  const int c0 = cg * 16;
  const int b0 = bg * 32;
  const int tid = threadIdx.x;
  const int wave = tid >> 6, lane = tid & 63;
  const int lq = lane >> 4, ln16 = lane & 15;

  __shared__ u16 Wi[48 * 520];   // pad 520: 16B-aligned rows, 2-way-max alias
  __shared__ u16 Wh[48 * 520];
  __shared__ u16 Hs[32 * 520];   // staged masked h_{t-1} (bf16)
  __shared__ float scr[2][32][52];
  __shared__ float biasl[2][48];

  for (int q = tid; q < 48 * 64; q += 256) {
    int row = q >> 6;
    int ch = (q & 63) * 8;
    int gr = (row >> 4) * 512 + c0 + (row & 15);   // gate-major weight row
    *(short8*)(&Wi[row * 520 + ch]) = *(const short8*)(wih + gr * 512 + ch);
    *(short8*)(&Wh[row * 520 + ch]) = *(const short8*)(whh + gr * 512 + ch);
  }
  if (tid < 96) {
    int g = (tid >= 48) ? 1 : 0;
    int i = tid - g * 48;
    const float* src = g ? bhh : bih;
    biasl[g][i] = src[(i >> 4) * 512 + c0 + (i & 15)];
  }
  __syncthreads();

  // unit descriptors: u = wave + ui*4 over 12 units (2 gemms x 2 m-tiles x 3 n-tiles)
  int ug[3], umt[3], unt[3];
#pragma unroll
  for (int ui = 0; ui < 3; ++ui) {
    int u = wave + ui * 4;
    ug[ui] = u / 6;
    int rem = u % 6;
    umt[ui] = rem / 3;
    unt[ui] = rem % 3;
  }

  float hprev[2] = {0.f, 0.f};   // fp32 recurrent state for e=tid, e=tid+256

  for (int t = 0; t < TD; ++t) {
    // --- gi units (independent of h; run before sync to hide latency) ---
#pragma unroll
    for (int ui = 0; ui < 3; ++ui) {
      if (ug[ui] != 0) continue;
      float4v acc = {0.f, 0.f, 0.f, 0.f};
      const int b = b0 + umt[ui] * 16 + ln16;
      const u16* arp = emb + (b * 512 + t) * 512 + lq * 8;
      const u16* brp = &Wi[(unt[ui] * 16 + ln16) * 520 + lq * 8];
#pragma unroll
      for (int kk = 0; kk < 16; ++kk) {
        short8 af = *(const short8*)(arp + kk * 32);
        short8 bf = *(const short8*)(brp + kk * 32);
        acc = __builtin_amdgcn_mfma_f32_16x16x32_bf16(af, bf, acc, 0, 0, 0);
      }
#pragma unroll
      for (int r = 0; r < 4; ++r)
        scr[0][umt[ui] * 16 + lq * 4 + r][unt[ui] * 16 + ln16] = acc[r];
    }

    // --- wait for all 32 channel blocks of this batch group to finish step t-1 ---
    if (t > 0) {
      const int* cp = cnt + bg * 512 + (t - 1);
      int guard = 0;
      while (__hip_atomic_load(cp, __ATOMIC_RELAXED, __HIP_MEMORY_SCOPE_AGENT) < 32) {
        if (++guard > (1 << 18)) break;   // fail-safe: never hang the bench
      }
    }

    // --- stage masked h_{t-1} (bf16, packed u64 = 4 ch) into LDS via coherent loads ---
    {
      int slot = (t & 1) ? 32768 : 0;   // (t-1)&1 selects producer slot; see write side
      slot = ((t - 1) & 1) * 32768;
#pragma unroll
      for (int i = 0; i < 16; ++i) {
        int q = tid + i * 256;          // 4096 u64 chunks: 32 rows x 128
        int row = q >> 7;
        int cw = q & 127;               // u64 index within row (4 channels each)
        int b = b0 + row;
        bool dn = dones[b * 512 + t] != 0;
        u64 v = 0;
        if (!dn) {
          if (t == 0) {
            const float* hp = hidden + b * 512 + cw * 4;
            float4v h4 = *(const float4v*)hp;
            v = (u64)f2bf(h4[0]) | ((u64)f2bf(h4[1]) << 16) |
                ((u64)f2bf(h4[2]) << 32) | ((u64)f2bf(h4[3]) << 48);
          } else {
            v = __hip_atomic_load(&hpk[slot + b * 128 + cw],
                                  __ATOMIC_RELAXED, __HIP_MEMORY_SCOPE_AGENT);
          }
        }
        *(u64*)(&Hs[row * 520 + cw * 4]) = v;
      }
    }
    __syncthreads();

    // --- gh units ---
#pragma unroll
    for (int ui = 0; ui < 3; ++ui) {
      if (ug[ui] != 1) continue;
      float4v acc = {0.f, 0.f, 0.f, 0.f};
      const u16* arp = &Hs[(umt[ui] * 16 + ln16) * 520 + lq * 8];
      const u16* brp = &Wh[(unt[ui] * 16 + ln16) * 520 + lq * 8];
#pragma unroll
      for (int kk = 0; kk < 16; ++kk) {
        short8 af = *(const short8*)(arp + kk * 32);
        short8 bf = *(const short8*)(brp + kk * 32);
        acc = __builtin_amdgcn_mfma_f32_16x16x32_bf16(af, bf, acc, 0, 0, 0);
      }
#pragma unroll
      for (int r = 0; r < 4; ++r)
        scr[1][umt[ui] * 16 + lq * 4 + r][unt[ui] * 16 + ln16] = acc[r];
    }
    __syncthreads();

    // --- elementwise GRU cell (fp32 state in registers) ---
#pragma unroll
    for (int it = 0; it < 2; ++it) {
      int e = tid + it * 256;
      int m = e >> 4, c = e & 15;
      int b = b0 + m;
      bool dn = dones[b * 512 + t] != 0;
      float h = dn ? 0.f : ((t == 0) ? hidden[b * 512 + c0 + c] : hprev[it]);
      float ir  = scr[0][m][c]      + biasl[0][c];
      float iz  = scr[0][m][c + 16] + biasl[0][c + 16];
      float inn = scr[0][m][c + 32] + biasl[0][c + 32];
      float hr  = scr[1][m][c]      + biasl[1][c];
      float hz  = scr[1][m][c + 16] + biasl[1][c + 16];
      float hn  = scr[1][m][c + 32] + biasl[1][c + 32];
      float rg = 1.f / (1.f + expf(-(ir + hr)));
      float z  = 1.f / (1.f + expf(-(iz + hz)));
      float nn = tanhf(inn + rg * hn);
      float hv = (1.f - z) * nn + z * h;
      hprev[it] = hv;
      outs[(t * 256 + b) * 512 + c0 + c] = hv;
      // pack 4 adjacent channels across lanes -> one coherent u64 store per 4 lanes
      unsigned mybf = f2bf(hv);
      unsigned o1 = (unsigned)__shfl_xor((int)mybf, 1);
      unsigned pk32 = (mybf & 0xffffu) | (o1 << 16);          // valid on even lanes: [c, c+1]
      unsigned pk32b = (unsigned)__shfl_xor((int)pk32, 2);    // [c+2, c+3] for (tid&3)==0
      if ((tid & 3) == 0) {
        u64 pv = (u64)pk32 | ((u64)pk32b << 32);
        __hip_atomic_store(&hpk[(t & 1) * 32768 + b * 128 + ((c0 + c) >> 2)], pv,
                           __ATOMIC_RELAXED, __HIP_MEMORY_SCOPE_AGENT);
      }
      if (t == TD - 1) hfin[b * 512 + c0 + c] = hv;
    }
    __builtin_amdgcn_s_waitcnt(0);   // per-wave drain: all sc1 stores at coherent point
    __syncthreads();                 // every wave drained before the release below

    if (tid == 0 && t < TD - 1) {
      __hip_atomic_fetch_add(cnt + bg * 512 + t, 1,
                             __ATOMIC_RELAXED, __HIP_MEMORY_SCOPE_AGENT);
    }
  }
}

// ---------------- final A=16 projection + avail mask ----------------
__global__ __launch_bounds__(256) void head_logits(
    const u16* __restrict__ am, const float* __restrict__ w2,
    const float* __restrict__ b2, const float* __restrict__ avail,
    float* __restrict__ out) {
  int r = blockIdx.x * 16 + (threadIdx.x >> 4);   // row in (t,b) order
  int a = threadIdx.x & 15;
  int t = r >> 8, b = r & 255;
  const u16* ar = am + r * 512;
  const float* wr = w2 + a * 512;
  float acc = 0.f;
  for (int k = 0; k < 512; k += 8) {
    short8 v = *(const short8*)(ar + k);
    float4v w0 = *(const float4v*)(wr + k);
    float4v w1 = *(const float4v*)(wr + k + 4);
    acc += bf2f((u16)v[0]) * w0[0] + bf2f((u16)v[1]) * w0[1] +
           bf2f((u16)v[2]) * w0[2] + bf2f((u16)v[3]) * w0[3] +
           bf2f((u16)v[4]) * w1[0] + bf2f((u16)v[5]) * w1[1] +
           bf2f((u16)v[6]) * w1[2] + bf2f((u16)v[7]) * w1[3];
  }
  int oi = (b * 512 + t) * 16 + a;   // [B,T,A] flat
  float avv = avail[oi];
  out[oi] = acc + b2[a] - (1.f - avv) * 1e10f;
}

extern "C" void kernel_launch(void* const* d_in, const int* in_sizes, int n_in,
                              void* d_out, int out_size, void* d_ws, size_t ws_size,
                              hipStream_t stream) {
  (void)in_sizes; (void)n_in; (void)out_size; (void)ws_size;
  const float* hidden = (const float*)d_in[0];
  const float* obs    = (const float*)d_in[1];
  const int*   dones  = (const int*)d_in[2];
  const float* avail  = (const float*)d_in[3];
  const float* in_w   = (const float*)d_in[4];
  const float* in_b   = (const float*)d_in[5];
  const float* ln_g   = (const float*)d_in[6];
  const float* ln_b   = (const float*)d_in[7];
  const float* gwih   = (const float*)d_in[8];
  const float* gwhh   = (const float*)d_in[9];
  const float* gbih   = (const float*)d_in[10];
  const float* gbhh   = (const float*)d_in[11];
  const float* am1w   = (const float*)d_in[12];
  const float* am1b   = (const float*)d_in[13];
  const float* amg    = (const float*)d_in[14];
  const float* amb    = (const float*)d_in[15];
  const float* am2w   = (const float*)d_in[16];
  const float* am2b   = (const float*)d_in[17];

  char* ws = (char*)d_ws;
  u16*   embA  = (u16*)(ws);                       // 128 MiB [B*T,512] bf16
  u16*   embB  = (u16*)(ws + 134217728);           // 128 MiB
  float* outs  = (float*)(ws + 268435456);         // 256 MiB [T,B,512] f32
  u16*   w_in  = (u16*)(ws + 536870912);           // bf16 weights
  u16*   w_ih  = w_in + 786432;
  u16*   w_hh  = w_ih + 786432;
  u16*   w_a1  = w_hh + 786432;
  int*   cnt   = (int*)(ws + 536870912 + 5242880); // 16 KiB per-(bg,t) counters
  u64*   hpk   = (u64*)(ws + 536870912 + 5242880 + 16384); // 512 KiB h ping-pong (packed bf16)

  hipMemsetAsync(cnt, 0, 16384, stream);
  cvt_bf16<<<1024, 256, 0, stream>>>(in_w, w_in, 786432);
  cvt_bf16<<<1024, 256, 0, stream>>>(gwih, w_ih, 786432);
  cvt_bf16<<<1024, 256, 0, stream>>>(gwhh, w_hh, 786432);
  cvt_bf16<<<512, 256, 0, stream>>>(am1w, w_a1, 262144);

  // MLP: Linear -> LN -> ReLU x3  (rows in (b,t) order, same as obs)
  gemm_ln_relu<true ><<<2048, 256, 0, stream>>>(obs,  w_in,          in_b,        ln_g,        ln_b,        embA);
  gemm_ln_relu<false><<<2048, 256, 0, stream>>>(embA, w_in + 262144, in_b + 512,  ln_g + 512,  ln_b + 512,  embB);
  gemm_ln_relu<false><<<2048, 256, 0, stream>>>(embB, w_in + 524288, in_b + 1024, ln_g + 1024, ln_b + 1024, embA);

  // GRU scan (persistent, 256 blocks, fence-free coherent-point sync)
  gru_scan<<<256, 256, 0, stream>>>(embA, w_ih, w_hh, gbih, gbhh, hidden, dones,
                                    outs, (float*)d_out, hpk, cnt);

  // actor head: Linear -> LN -> ReLU (rows in (t,b) order), then A=16 projection + mask
  gemm_ln_relu<true ><<<2048, 256, 0, stream>>>(outs, w_a1, am1b, amg, amb, embB);
  head_logits<<<8192, 256, 0, stream>>>(embB, am2w, am2b, avail, (float*)d_out + 131072);
}

// Round 3
// 4751.934 us; speedup vs baseline: 5.0166x; 1.5961x over previous
//
#include <hip/hip_runtime.h>

// Problem constants (H=512, A=16, L=3, B=256, T=512)
#define HD 512
#define AD 16
#define BD 256
#define TD 512

using short8  = __attribute__((ext_vector_type(8))) short;
using float4v = __attribute__((ext_vector_type(4))) float;
using ushort4v = __attribute__((ext_vector_type(4))) unsigned short;
typedef unsigned short u16;
typedef unsigned long long u64;

__device__ __forceinline__ u16 f2bf(float f) {
  union { float f; unsigned u; } v; v.f = f;
  unsigned r = v.u + 0x7fffu + ((v.u >> 16) & 1u);
  return (u16)(r >> 16);
}
__device__ __forceinline__ float bf2f(u16 u) {
  union { unsigned u; float f; } c; c.u = ((unsigned)u) << 16; return c.f;
}

// ---------------- fp32 -> bf16 convert ----------------
__global__ __launch_bounds__(256) void cvt_bf16(const float* __restrict__ in,
                                                u16* __restrict__ out, int n) {
  int i = blockIdx.x * 256 + threadIdx.x;
  int stride = gridDim.x * 256;
  for (; i < n; i += stride) out[i] = f2bf(in[i]);
}

// ---------------- GEMM (M x 512) @ (512 x 512)^T + bias -> LayerNorm -> ReLU -> bf16 ----------------
template <bool AF32>
__global__ __launch_bounds__(256) void gemm_ln_relu(
    const void* __restrict__ Ap, const u16* __restrict__ W,
    const float* __restrict__ bias, const float* __restrict__ gam,
    const float* __restrict__ bet, u16* __restrict__ Y) {
  const int r0 = blockIdx.x * 64;
  const int tid = threadIdx.x;
  const int wave = tid >> 6, lane = tid & 63;
  const int lq = lane >> 4, ln16 = lane & 15;

  __shared__ u16 As[64 * 40];
  __shared__ u16 Bs[512 * 40];
  __shared__ float partial[64][4][2];
  __shared__ float murs[64][2];

  float4v acc[4][8];
#pragma unroll
  for (int i = 0; i < 4; ++i)
#pragma unroll
    for (int j = 0; j < 8; ++j) acc[i][j] = (float4v){0.f, 0.f, 0.f, 0.f};

  for (int kk = 0; kk < 16; ++kk) {
    __syncthreads();
    if (AF32) {
      const float* Af = (const float*)Ap;
#pragma unroll
      for (int it = 0; it < 2; ++it) {
        int q = tid + it * 256;
        int row = q >> 3, ko = (q & 7) * 4;
        float4v v = *(const float4v*)(Af + (r0 + row) * 512 + kk * 32 + ko);
        ushort4v o;
        o[0] = f2bf(v[0]); o[1] = f2bf(v[1]); o[2] = f2bf(v[2]); o[3] = f2bf(v[3]);
        *(ushort4v*)(&As[row * 40 + ko]) = o;
      }
    } else {
      const u16* Ab = (const u16*)Ap;
      int row = tid >> 2, ko = (tid & 3) * 8;
      *(short8*)(&As[row * 40 + ko]) =
          *(const short8*)(Ab + (r0 + row) * 512 + kk * 32 + ko);
    }
#pragma unroll
    for (int it = 0; it < 8; ++it) {
      int q = tid + it * 256;
      int row = q >> 2, ko = (q & 3) * 8;
      *(short8*)(&Bs[row * 40 + ko]) =
          *(const short8*)(W + row * 512 + kk * 32 + ko);
    }
    __syncthreads();
    short8 afr[4];
#pragma unroll
    for (int mt = 0; mt < 4; ++mt)
      afr[mt] = *(const short8*)(&As[(mt * 16 + ln16) * 40 + lq * 8]);
#pragma unroll
    for (int nt = 0; nt < 8; ++nt) {
      short8 bfr = *(const short8*)(&Bs[(wave * 128 + nt * 16 + ln16) * 40 + lq * 8]);
#pragma unroll
      for (int mt = 0; mt < 4; ++mt)
        acc[mt][nt] = __builtin_amdgcn_mfma_f32_16x16x32_bf16(afr[mt], bfr, acc[mt][nt], 0, 0, 0);
    }
  }

  float gv[8], bv[8], av[8];
#pragma unroll
  for (int nt = 0; nt < 8; ++nt) {
    int c = wave * 128 + nt * 16 + ln16;
    gv[nt] = gam[c]; bv[nt] = bet[c]; av[nt] = bias[c];
  }
#pragma unroll
  for (int mt = 0; mt < 4; ++mt)
#pragma unroll
    for (int nt = 0; nt < 8; ++nt)
#pragma unroll
      for (int r = 0; r < 4; ++r) acc[mt][nt][r] += av[nt];

#pragma unroll
  for (int mt = 0; mt < 4; ++mt) {
#pragma unroll
    for (int r = 0; r < 4; ++r) {
      float s = 0.f, ss = 0.f;
#pragma unroll
      for (int nt = 0; nt < 8; ++nt) { float v = acc[mt][nt][r]; s += v; ss += v * v; }
#pragma unroll
      for (int off = 1; off < 16; off <<= 1) { s += __shfl_xor(s, off); ss += __shfl_xor(ss, off); }
      if (ln16 == 0) {
        int m = mt * 16 + lq * 4 + r;
        partial[m][wave][0] = s; partial[m][wave][1] = ss;
      }
    }
  }
  __syncthreads();
  if (tid < 64) {
    float s = partial[tid][0][0] + partial[tid][1][0] + partial[tid][2][0] + partial[tid][3][0];
    float ss = partial[tid][0][1] + partial[tid][1][1] + partial[tid][2][1] + partial[tid][3][1];
    float mu = s * (1.f / 512.f);
    float var = ss * (1.f / 512.f) - mu * mu;
    murs[tid][0] = mu;
    murs[tid][1] = rsqrtf(var + 1e-5f);
  }
  __syncthreads();
#pragma unroll
  for (int mt = 0; mt < 4; ++mt) {
#pragma unroll
    for (int r = 0; r < 4; ++r) {
      int m = mt * 16 + lq * 4 + r;
      float mu = murs[m][0], rs = murs[m][1];
#pragma unroll
      for (int nt = 0; nt < 8; ++nt) {
        int c = wave * 128 + nt * 16 + ln16;
        float v = (acc[mt][nt][r] - mu) * rs * gv[nt] + bv[nt];
        Y[(r0 + m) * 512 + c] = f2bf(fmaxf(v, 0.f));
      }
    }
  }
}

// ---------------- persistent GRU scan v3: wave-specialized, barrier-free critical path -------------
// 256 blocks = 8 bg x 32 cb. Block = 32 batch rows x 16 channels, 4 waves:
//   waves 0,1 = ENGINE (mt = wave): h A-frag loaded sc1 -> registers, 48 gh MFMAs (Whh in
//     swizzled LDS), gate math fully in MFMA C-layout registers (gi from LDS ring), pack ->
//     sc1 store -> per-wave s_waitcnt(0) -> per-(bg,mt,t) flag release. NO barrier on this path.
//   waves 2,3 = PRODUCER (mt = wave-2): gi(t+1) = emb @ Wih^T into double-buffered scr ring.
//     Wih streamed from global (L2-resident), emb from L2/HBM. One __syncthreads per step, after
//     the release.
// Two independent 16-row chains per bg (per-mt counters, 32 producers each).
__global__ __launch_bounds__(256) void gru_scan(
    const u16* __restrict__ emb, const u16* __restrict__ wih,
    const u16* __restrict__ whh, const float* __restrict__ bih,
    const float* __restrict__ bhh, const float* __restrict__ hidden,
    const int* __restrict__ dones, float* __restrict__ outs,
    float* __restrict__ hfin, u64* __restrict__ hpk, int* __restrict__ cnt) {
  const int bg = blockIdx.x >> 5;
  const int cg = blockIdx.x & 31;
  const int c0 = cg * 16;
  const int b0 = bg * 32;
  const int tid = threadIdx.x;
  const int wave = tid >> 6, lane = tid & 63;
  const int lq = lane >> 4, ln16 = lane & 15;

  __shared__ u16 Wh[48 * 512];            // 48 gate-rows x 512 K, XOR-swizzled 16B chunks
  __shared__ float scr[2][2][3][16][18];  // [parity][mt][gate][row][col(+pad)]

  // ---- Whh -> LDS, swizzled: chunk' = chunk ^ (row & 7) ----
  for (int q = tid; q < 48 * 64; q += 256) {
    int rr = q >> 6, c = q & 63;
    int gate = rr >> 4, chl = rr & 15;
    int phys = c ^ (rr & 7);
    *(short8*)(&Wh[rr * 512 + phys * 8]) =
        *(const short8*)(whh + (gate * 512 + c0 + chl) * 512 + c * 8);
  }

  // gi producer: gi(tp) for this block's tile mt -> scr[tp&1][mt]
  auto produce = [&](int tp, int mt) {
    int row = b0 + mt * 16 + ln16;
    const u16* ap = emb + (row * 512 + tp) * 512 + lq * 8;
    float4v acc[3];
#pragma unroll
    for (int g = 0; g < 3; ++g) acc[g] = (float4v){0.f, 0.f, 0.f, 0.f};
#pragma unroll
    for (int kk = 0; kk < 16; ++kk) {
      short8 af = *(const short8*)(ap + kk * 32);
#pragma unroll
      for (int g = 0; g < 3; ++g) {
        short8 bf = *(const short8*)(wih + (g * 512 + c0 + ln16) * 512 + lq * 8 + kk * 32);
        acc[g] = __builtin_amdgcn_mfma_f32_16x16x32_bf16(af, bf, acc[g], 0, 0, 0);
      }
    }
#pragma unroll
    for (int g = 0; g < 3; ++g)
#pragma unroll
      for (int r = 0; r < 4; ++r)
        scr[tp & 1][mt][g][lq * 4 + r][ln16] = acc[g][r];
  };

  if (wave >= 2) produce(0, wave - 2);   // prime the gi ring
  __syncthreads();

  if (wave < 2) {
    // ================= ENGINE =================
    const int mt = wave;
    const int rowA = b0 + mt * 16 + ln16;          // batch row this lane's A-frag covers
    float bi[3], bhv[3];
#pragma unroll
    for (int g = 0; g < 3; ++g) {
      bi[g]  = bih[g * 512 + c0 + ln16];
      bhv[g] = bhh[g * 512 + c0 + ln16];
    }
    float hprev[4];
#pragma unroll
    for (int r = 0; r < 4; ++r)
      hprev[r] = hidden[(b0 + mt * 16 + lq * 4 + r) * 512 + c0 + ln16];

    int* mycnt = cnt + (bg * 2 + mt) * 512;

    for (int t = 0; t < TD; ++t) {
      // off-path prefetches (independent of the flag)
      bool dn = dones[rowA * 512 + t] != 0;
      int dn_i = dn ? 1 : 0;
      float giv[3][4];
#pragma unroll
      for (int g = 0; g < 3; ++g)
#pragma unroll
        for (int r = 0; r < 4; ++r) giv[g][r] = scr[t & 1][mt][g][lq * 4 + r][ln16];

      // wait for step t-1 of this mt-chain (32 producer waves)
      if (t > 0) {
        const int* cp = mycnt + (t - 1);
        int guard = 0;
        while (__hip_atomic_load(cp, __ATOMIC_RELAXED, __HIP_MEMORY_SCOPE_AGENT) < 32) {
          if (++guard > (1 << 18)) break;
        }
      }

      // h_{t-1} A-fragment straight into registers (coherent loads)
      u64 av[32];
      if (t == 0) {
#pragma unroll
        for (int kk = 0; kk < 16; ++kk) {
          const float* hp = hidden + rowA * 512 + lq * 8 + kk * 32;
          float4v h0 = *(const float4v*)(hp);
          float4v h1 = *(const float4v*)(hp + 4);
          av[2 * kk] = (u64)f2bf(h0[0]) | ((u64)f2bf(h0[1]) << 16) |
                       ((u64)f2bf(h0[2]) << 32) | ((u64)f2bf(h0[3]) << 48);
          av[2 * kk + 1] = (u64)f2bf(h1[0]) | ((u64)f2bf(h1[1]) << 16) |
                           ((u64)f2bf(h1[2]) << 32) | ((u64)f2bf(h1[3]) << 48);
        }
      } else {
        const u64* hb = hpk + ((t - 1) & 1) * 32768 + rowA * 128 + lq * 2;
#pragma unroll
        for (int kk = 0; kk < 16; ++kk) {
          av[2 * kk]     = __hip_atomic_load(hb + kk * 8,     __ATOMIC_RELAXED, __HIP_MEMORY_SCOPE_AGENT);
          av[2 * kk + 1] = __hip_atomic_load(hb + kk * 8 + 1, __ATOMIC_RELAXED, __HIP_MEMORY_SCOPE_AGENT);
        }
      }
#pragma unroll
      for (int i = 0; i < 32; ++i) av[i] = dn ? 0ull : av[i];

      // gh = h @ Whh_slice^T  (3 gates)
      float4v agh[3];
#pragma unroll
      for (int g = 0; g < 3; ++g) agh[g] = (float4v){0.f, 0.f, 0.f, 0.f};
#pragma unroll
      for (int kk = 0; kk < 16; ++kk) {
        union { u64 q[2]; short8 v; } u;
        u.q[0] = av[2 * kk]; u.q[1] = av[2 * kk + 1];
#pragma unroll
        for (int g = 0; g < 3; ++g) {
          int rr = g * 16 + ln16;
          int phys = (lq + 4 * kk) ^ (rr & 7);
          short8 bf = *(const short8*)(&Wh[rr * 512 + phys * 8]);
          agh[g] = __builtin_amdgcn_mfma_f32_16x16x32_bf16(u.v, bf, agh[g], 0, 0, 0);
        }
      }

      // gate math in C-layout registers
      float hv[4];
#pragma unroll
      for (int r = 0; r < 4; ++r) {
        int dnc = __shfl(dn_i, lq * 4 + r);
        float h = dnc ? 0.f : hprev[r];
        float ir  = giv[0][r] + bi[0];
        float iz  = giv[1][r] + bi[1];
        float inn = giv[2][r] + bi[2];
        float hr  = agh[0][r] + bhv[0];
        float hz  = agh[1][r] + bhv[1];
        float hn  = agh[2][r] + bhv[2];
        float rg = 1.f / (1.f + expf(-(ir + hr)));
        float z  = 1.f / (1.f + expf(-(iz + hz)));
        float nn = tanhf(inn + rg * hn);
        hv[r] = (1.f - z) * nn + z * h;
        hprev[r] = hv[r];
      }

      // pack 4 adjacent channels -> u64, coherent store; plus outs/hfin (drained together)
#pragma unroll
      for (int r = 0; r < 4; ++r) {
        unsigned mybf = f2bf(hv[r]);
        unsigned o1 = (unsigned)__shfl((int)mybf, lane ^ 1);
        unsigned pk = (mybf & 0xffffu) | (o1 << 16);
        unsigned pk2 = (unsigned)__shfl((int)pk, lane ^ 2);
        int b = b0 + mt * 16 + lq * 4 + r;
        if ((ln16 & 3) == 0) {
          u64 pv = (u64)pk | ((u64)pk2 << 32);
          __hip_atomic_store(hpk + (t & 1) * 32768 + b * 128 + ((c0 + ln16) >> 2), pv,
                             __ATOMIC_RELAXED, __HIP_MEMORY_SCOPE_AGENT);
        }
        outs[(t * 256 + b) * 512 + c0 + ln16] = hv[r];
        if (t == TD - 1) hfin[b * 512 + c0 + ln16] = hv[r];
      }
      __builtin_amdgcn_s_waitcnt(0);     // this wave's stores are at the coherent point
      if (lane == 0 && t < TD - 1)
        __hip_atomic_fetch_add(mycnt + t, 1, __ATOMIC_RELAXED, __HIP_MEMORY_SCOPE_AGENT);

      __syncthreads();                   // swap gi ring with producers
    }
  } else {
    // ================= PRODUCER =================
    const int mt = wave - 2;
    for (int t = 0; t < TD; ++t) {
      if (t + 1 < TD) produce(t + 1, mt);
      __syncthreads();
    }
  }
}

// ---------------- final A=16 projection + avail mask ----------------
__global__ __launch_bounds__(256) void head_logits(
    const u16* __restrict__ am, const float* __restrict__ w2,
    const float* __restrict__ b2, const float* __restrict__ avail,
    float* __restrict__ out) {
  int r = blockIdx.x * 16 + (threadIdx.x >> 4);
  int a = threadIdx.x & 15;
  int t = r >> 8, b = r & 255;
  const u16* ar = am + r * 512;
  const float* wr = w2 + a * 512;
  float acc = 0.f;
  for (int k = 0; k < 512; k += 8) {
    short8 v = *(const short8*)(ar + k);
    float4v w0 = *(const float4v*)(wr + k);
    float4v w1 = *(const float4v*)(wr + k + 4);
    acc += bf2f((u16)v[0]) * w0[0] + bf2f((u16)v[1]) * w0[1] +
           bf2f((u16)v[2]) * w0[2] + bf2f((u16)v[3]) * w0[3] +
           bf2f((u16)v[4]) * w1[0] + bf2f((u16)v[5]) * w1[1] +
           bf2f((u16)v[6]) * w1[2] + bf2f((u16)v[7]) * w1[3];
  }
  int oi = (b * 512 + t) * 16 + a;
  float avv = avail[oi];
  out[oi] = acc + b2[a] - (1.f - avv) * 1e10f;
}

extern "C" void kernel_launch(void* const* d_in, const int* in_sizes, int n_in,
                              void* d_out, int out_size, void* d_ws, size_t ws_size,
                              hipStream_t stream) {
  (void)in_sizes; (void)n_in; (void)out_size; (void)ws_size;
  const float* hidden = (const float*)d_in[0];
  const float* obs    = (const float*)d_in[1];
  const int*   dones  = (const int*)d_in[2];
  const float* avail  = (const float*)d_in[3];
  const float* in_w   = (const float*)d_in[4];
  const float* in_b   = (const float*)d_in[5];
  const float* ln_g   = (const float*)d_in[6];
  const float* ln_b   = (const float*)d_in[7];
  const float* gwih   = (const float*)d_in[8];
  const float* gwhh   = (const float*)d_in[9];
  const float* gbih   = (const float*)d_in[10];
  const float* gbhh   = (const float*)d_in[11];
  const float* am1w   = (const float*)d_in[12];
  const float* am1b   = (const float*)d_in[13];
  const float* amg    = (const float*)d_in[14];
  const float* amb    = (const float*)d_in[15];
  const float* am2w   = (const float*)d_in[16];
  const float* am2b   = (const float*)d_in[17];

  char* ws = (char*)d_ws;
  u16*   embA  = (u16*)(ws);                       // 128 MiB [B*T,512] bf16
  u16*   embB  = (u16*)(ws + 134217728);           // 128 MiB
  float* outs  = (float*)(ws + 268435456);         // 256 MiB [T,B,512] f32
  u16*   w_in  = (u16*)(ws + 536870912);           // bf16 weights
  u16*   w_ih  = w_in + 786432;
  u16*   w_hh  = w_ih + 786432;
  u16*   w_a1  = w_hh + 786432;
  int*   cnt   = (int*)(ws + 536870912 + 5242880); // 32 KiB per-(bg,mt,t) counters
  u64*   hpk   = (u64*)(ws + 536870912 + 5242880 + 32768); // 512 KiB h ping-pong (packed bf16)

  hipMemsetAsync(cnt, 0, 32768, stream);
  cvt_bf16<<<1024, 256, 0, stream>>>(in_w, w_in, 786432);
  cvt_bf16<<<1024, 256, 0, stream>>>(gwih, w_ih, 786432);
  cvt_bf16<<<1024, 256, 0, stream>>>(gwhh, w_hh, 786432);
  cvt_bf16<<<512, 256, 0, stream>>>(am1w, w_a1, 262144);

  // MLP: Linear -> LN -> ReLU x3  (rows in (b,t) order, same as obs)
  gemm_ln_relu<true ><<<2048, 256, 0, stream>>>(obs,  w_in,          in_b,        ln_g,        ln_b,        embA);
  gemm_ln_relu<false><<<2048, 256, 0, stream>>>(embA, w_in + 262144, in_b + 512,  ln_g + 512,  ln_b + 512,  embB);
  gemm_ln_relu<false><<<2048, 256, 0, stream>>>(embB, w_in + 524288, in_b + 1024, ln_g + 1024, ln_b + 1024, embA);

  // GRU scan (persistent, 256 blocks, wave-specialized fence-free sync)
  gru_scan<<<256, 256, 0, stream>>>(embA, w_ih, w_hh, gbih, gbhh, hidden, dones,
                                    outs, (float*)d_out, hpk, cnt);

  // actor head: Linear -> LN -> ReLU (rows in (t,b) order), then A=16 projection + mask
  gemm_ln_relu<true ><<<2048, 256, 0, stream>>>(outs, w_a1, am1b, amg, amb, embB);
  head_logits<<<8192, 256, 0, stream>>>(embB, am2w, am2b, avail, (float*)d_out + 131072);
}